// Round 1
// baseline (661.911 us; speedup 1.0000x reference)
//
#include <hip/hip_runtime.h>
#include <math.h>

#define NN 50000
#define EE 400000
#define ETOT 450000
#define INC 128
#define HH 4
#define CC 64
#define HC 256
#define ELI_N 200000

// ---------------- CSR build ----------------
__global__ void k_init_deg(int* deg){
    int i = blockIdx.x*256 + threadIdx.x;
    if (i < NN) deg[i] = 1;          // self-loop
}

__global__ void k_count(const int* __restrict__ ei, int* __restrict__ deg){
    int e = blockIdx.x*256 + threadIdx.x;
    if (e < EE) atomicAdd(&deg[ei[EE + e]], 1);
}

// chunk=1024 per block (256 thr x 4), inclusive scan within chunk
__global__ void k_scanA(const int* __restrict__ deg, int* __restrict__ iscan, int* __restrict__ part){
    __shared__ int sh[256];
    int tid = threadIdx.x;
    int base = blockIdx.x*1024 + tid*4;
    int v[4]; int t = 0;
    #pragma unroll
    for (int i = 0; i < 4; i++){ int idx = base + i; v[i] = (idx < NN) ? deg[idx] : 0; t += v[i]; }
    sh[tid] = t; __syncthreads();
    for (int off = 1; off < 256; off <<= 1){
        int u = (tid >= off) ? sh[tid - off] : 0;
        __syncthreads();
        sh[tid] += u;
        __syncthreads();
    }
    int incl = sh[tid];
    int run = incl - t;          // exclusive prefix of this thread
    #pragma unroll
    for (int i = 0; i < 4; i++){
        run += v[i];
        int idx = base + i;
        if (idx < NN) iscan[idx] = run;
    }
    if (tid == 255) part[blockIdx.x] = incl;
}

__global__ void k_scanB(int* part, int nb){
    if (threadIdx.x == 0){
        int r = 0;
        for (int i = 0; i < nb; i++){ int t = part[i]; part[i] = r; r += t; }
    }
}

__global__ void k_scanC(const int* __restrict__ iscan, const int* __restrict__ part, int* __restrict__ rowptr){
    int i = blockIdx.x*256 + threadIdx.x;
    if (i < NN) rowptr[i+1] = iscan[i] + part[i >> 10];
    if (i == 0) rowptr[0] = 0;
}

__global__ void k_cursor(const int* __restrict__ rowptr, int* __restrict__ cursor){
    int i = blockIdx.x*256 + threadIdx.x;
    if (i < NN) cursor[i] = rowptr[i];
}

__global__ void k_fill(const int* __restrict__ ei, int* __restrict__ cursor, int* __restrict__ csr_src){
    int idx = blockIdx.x*256 + threadIdx.x;
    if (idx >= ETOT) return;
    int s, d;
    if (idx < EE){ s = ei[idx]; d = ei[EE + idx]; }
    else         { s = idx - EE; d = s; }
    int pos = atomicAdd(&cursor[d], 1);
    csr_src[pos] = s;
}

// ---------------- fp32 GEMM: C[M,Nc] = A[M,K] @ W[K,Nc] + bias ----------------
__global__ __launch_bounds__(256) void k_gemm(const float* __restrict__ A, const float* __restrict__ W,
                                              const float* __restrict__ bias, float* __restrict__ Cout,
                                              int M, int K, int Nc)
{
    __shared__ float As[32][65];
    __shared__ float Ws[32][64];
    int tid = threadIdx.x;
    int tx = tid & 15, ty = tid >> 4;
    int rm0 = blockIdx.y * 64, n0 = blockIdx.x * 64;
    float acc[4][4] = {};
    for (int k0 = 0; k0 < K; k0 += 32){
        #pragma unroll
        for (int t = 0; t < 8; t++){
            int lid = tid + t*256;
            int m = lid >> 5, k = lid & 31;
            int gr = rm0 + m;
            As[k][m] = (gr < M) ? A[(size_t)gr*K + k0 + k] : 0.f;
        }
        #pragma unroll
        for (int t = 0; t < 8; t++){
            int lid = tid + t*256;
            int k = lid >> 6, n = lid & 63;
            Ws[k][n] = W[(size_t)(k0 + k)*Nc + n0 + n];
        }
        __syncthreads();
        #pragma unroll
        for (int k = 0; k < 32; k++){
            float a[4], w[4];
            #pragma unroll
            for (int i = 0; i < 4; i++) a[i] = As[k][ty + 16*i];
            #pragma unroll
            for (int j = 0; j < 4; j++) w[j] = Ws[k][tx + 16*j];
            #pragma unroll
            for (int i = 0; i < 4; i++)
                #pragma unroll
                for (int j = 0; j < 4; j++)
                    acc[i][j] += a[i] * w[j];
        }
        __syncthreads();
    }
    #pragma unroll
    for (int j = 0; j < 4; j++){
        float bv = bias[n0 + tx + 16*j];
        #pragma unroll
        for (int i = 0; i < 4; i++){
            int gr = rm0 + ty + 16*i;
            if (gr < M) Cout[(size_t)gr*Nc + n0 + tx + 16*j] = acc[i][j] + bv;
        }
    }
}

// ---------------- fused GATv2 aggregation (one wave per dst node, online softmax) -------------
__global__ __launch_bounds__(256) void k_gat(const float* __restrict__ xl, const float* __restrict__ xr,
                                             const int* __restrict__ csr_src, const int* __restrict__ rowptr,
                                             const float* __restrict__ att, const float* __restrict__ bias,
                                             float* __restrict__ out)
{
    int wave = threadIdx.x >> 6, lane = threadIdx.x & 63;
    int node = blockIdx.x*4 + wave;
    if (node >= NN) return;
    int p0 = rowptr[node], p1 = rowptr[node+1];
    float xr_f[4], att_f[4], m[4], s[4], acc[4];
    const float* xrp = xr + (size_t)node * HC;
    #pragma unroll
    for (int h = 0; h < 4; h++){
        xr_f[h]  = xrp[h*64 + lane];
        att_f[h] = att[h*64 + lane];
        m[h] = -INFINITY; s[h] = 0.f; acc[h] = 0.f;
    }
    for (int p = p0; p < p1; p++){
        int src = csr_src[p];
        const float* xlp = xl + (size_t)src * HC;
        float xv[4], lg[4];
        #pragma unroll
        for (int h = 0; h < 4; h++){
            xv[h] = xlp[h*64 + lane];
            float v = xv[h] + xr_f[h];
            v = (v > 0.f) ? v : 0.2f * v;
            lg[h] = v * att_f[h];
        }
        #pragma unroll
        for (int off = 32; off > 0; off >>= 1)
            #pragma unroll
            for (int h = 0; h < 4; h++) lg[h] += __shfl_xor(lg[h], off, 64);
        #pragma unroll
        for (int h = 0; h < 4; h++){
            float nm = fmaxf(m[h], lg[h]);
            float sc = __expf(m[h] - nm);
            float w  = __expf(lg[h] - nm);
            s[h]   = s[h]*sc + w;
            acc[h] = acc[h]*sc + w * xv[h];
            m[h]   = nm;
        }
    }
    float o = 0.f;
    #pragma unroll
    for (int h = 0; h < 4; h++) o += acc[h] / s[h];
    out[(size_t)node*CC + lane] = 0.25f * o + bias[lane];
}

// ---------------- BatchNorm ----------------
__global__ __launch_bounds__(256) void k_bnstats(const float* __restrict__ x, float* __restrict__ sums){
    __shared__ float ls[256], lq[256];
    int tid = threadIdx.x; int c = tid & 63; int g = tid >> 6;
    float s = 0.f, q = 0.f;
    for (int r = blockIdx.x*4 + g; r < NN; r += gridDim.x*4){
        float v = x[(size_t)r*64 + c]; s += v; q += v*v;
    }
    ls[tid] = s; lq[tid] = q; __syncthreads();
    if (tid < 64){
        s = ls[tid] + ls[tid+64] + ls[tid+128] + ls[tid+192];
        q = lq[tid] + lq[tid+64] + lq[tid+128] + lq[tid+192];
        atomicAdd(&sums[c], s); atomicAdd(&sums[64 + c], q);
    }
}

__global__ void k_bnfin(const float* __restrict__ sums, float* __restrict__ mr){
    int c = threadIdx.x;
    if (c < 64){
        float mean = sums[c] / (float)NN;
        float var  = sums[64 + c] / (float)NN - mean*mean;
        mr[c] = mean;
        mr[64 + c] = rsqrtf(var + 1e-5f);
    }
}

// h = relu(bn(hraw) + xres)
__global__ void k_post1(const float* __restrict__ hraw, const float* __restrict__ xres,
                        const float* __restrict__ mr, const float* __restrict__ g,
                        const float* __restrict__ b, float* __restrict__ out){
    int i = blockIdx.x*256 + threadIdx.x;   // float4 index
    if (i >= NN*16) return;
    float4 hv = ((const float4*)hraw)[i];
    float4 rv = ((const float4*)xres)[i];
    int c0 = (i & 15) * 4;
    float hp[4] = {hv.x, hv.y, hv.z, hv.w};
    float rp[4] = {rv.x, rv.y, rv.z, rv.w};
    float res[4];
    #pragma unroll
    for (int k = 0; k < 4; k++){
        int c = c0 + k;
        float v = g[c]*(hp[k] - mr[c])*mr[64 + c] + b[c] + rp[k];
        res[k] = (v > 0.f) ? v : 0.f;
    }
    ((float4*)out)[i] = make_float4(res[0], res[1], res[2], res[3]);
}

// z = bn(h2raw) + h
__global__ void k_post2(const float* __restrict__ hraw, const float* __restrict__ hprev,
                        const float* __restrict__ mr, const float* __restrict__ g,
                        const float* __restrict__ b, float* __restrict__ out){
    int i = blockIdx.x*256 + threadIdx.x;
    if (i >= NN*16) return;
    float4 hv = ((const float4*)hraw)[i];
    float4 rv = ((const float4*)hprev)[i];
    int c0 = (i & 15) * 4;
    float hp[4] = {hv.x, hv.y, hv.z, hv.w};
    float rp[4] = {rv.x, rv.y, rv.z, rv.w};
    float res[4];
    #pragma unroll
    for (int k = 0; k < 4; k++){
        int c = c0 + k;
        res[k] = g[c]*(hp[k] - mr[c])*mr[64 + c] + b[c] + rp[k];
    }
    ((float4*)out)[i] = make_float4(res[0], res[1], res[2], res[3]);
}

// ---------------- link-prediction scores ----------------
__global__ __launch_bounds__(256) void k_score(const float* __restrict__ z, const int* __restrict__ eli,
                                               float* __restrict__ out){
    int t = blockIdx.x*256 + threadIdx.x;
    int i = t >> 4; int j = t & 15;
    if (i >= ELI_N) return;
    int a = eli[i], b = eli[ELI_N + i];
    float4 va = ((const float4*)(z + (size_t)a*64))[j];
    float4 vb = ((const float4*)(z + (size_t)b*64))[j];
    float s = va.x*vb.x + va.y*vb.y + va.z*vb.z + va.w*vb.w;
    #pragma unroll
    for (int off = 8; off > 0; off >>= 1) s += __shfl_xor(s, off, 64);
    if (j == 0) out[i] = 1.f / (1.f + __expf(-s));
}

extern "C" void kernel_launch(void* const* d_in, const int* in_sizes, int n_in,
                              void* d_out, int out_size, void* d_ws, size_t ws_size,
                              hipStream_t stream) {
    const float* x    = (const float*)d_in[0];
    const int*   ei   = (const int*)  d_in[1];
    const int*   eli  = (const int*)  d_in[2];
    const float* Wl1  = (const float*)d_in[3];
    const float* bl1  = (const float*)d_in[4];
    const float* Wr1  = (const float*)d_in[5];
    const float* br1  = (const float*)d_in[6];
    const float* att1 = (const float*)d_in[7];
    const float* bias1= (const float*)d_in[8];
    const float* g1   = (const float*)d_in[9];
    const float* b1   = (const float*)d_in[10];
    const float* Wres = (const float*)d_in[11];
    const float* bres = (const float*)d_in[12];
    const float* Wl2  = (const float*)d_in[13];
    const float* bl2  = (const float*)d_in[14];
    const float* Wr2  = (const float*)d_in[15];
    const float* br2  = (const float*)d_in[16];
    const float* att2 = (const float*)d_in[17];
    const float* bias2= (const float*)d_in[18];
    const float* g2   = (const float*)d_in[19];
    const float* b2   = (const float*)d_in[20];
    float* out = (float*)d_out;

    float* ws = (float*)d_ws;
    size_t o = 0;
    float* xl   = ws + o; o += (size_t)NN*HC;   // 12.8M floats
    float* xr   = ws + o; o += (size_t)NN*HC;
    float* xres = ws + o; o += (size_t)NN*CC;   // later reused as z
    float* hraw = ws + o; o += (size_t)NN*CC;   // also layer2 raw out
    float* hbuf = ws + o; o += (size_t)NN*CC;
    float* stats= ws + o; o += 512;             // [sum1|mr1|sum2|mr2] x128
    int* ibase   = (int*)(ws + o);
    int* deg     = ibase;
    int* rowptr  = ibase + NN;
    int* cursor  = rowptr + (NN + 1);           // also iscan
    int* csr_src = cursor + NN;
    int* part    = csr_src + ETOT;              // 64 ints

    hipMemsetAsync(stats, 0, 512*sizeof(float), stream);

    // CSR build
    k_init_deg<<<(NN+255)/256, 256, 0, stream>>>(deg);
    k_count<<<(EE+255)/256, 256, 0, stream>>>(ei, deg);
    k_scanA<<<49, 256, 0, stream>>>(deg, cursor, part);
    k_scanB<<<1, 64, 0, stream>>>(part, 49);
    k_scanC<<<(NN+255)/256, 256, 0, stream>>>(cursor, part, rowptr);
    k_cursor<<<(NN+255)/256, 256, 0, stream>>>(rowptr, cursor);
    k_fill<<<(ETOT+255)/256, 256, 0, stream>>>(ei, cursor, csr_src);

    // layer 1
    dim3 gHC(4, (NN+63)/64);
    dim3 gC (1, (NN+63)/64);
    k_gemm<<<gHC, 256, 0, stream>>>(x, Wl1, bl1, xl, NN, INC, HC);
    k_gemm<<<gHC, 256, 0, stream>>>(x, Wr1, br1, xr, NN, INC, HC);
    k_gemm<<<gC,  256, 0, stream>>>(x, Wres, bres, xres, NN, INC, CC);
    k_gat<<<(NN+3)/4, 256, 0, stream>>>(xl, xr, csr_src, rowptr, att1, bias1, hraw);
    k_bnstats<<<256, 256, 0, stream>>>(hraw, stats);
    k_bnfin<<<1, 64, 0, stream>>>(stats, stats + 128);
    k_post1<<<(NN*16+255)/256, 256, 0, stream>>>(hraw, xres, stats + 128, g1, b1, hbuf);

    // layer 2
    k_gemm<<<gHC, 256, 0, stream>>>(hbuf, Wl2, bl2, xl, NN, CC, HC);
    k_gemm<<<gHC, 256, 0, stream>>>(hbuf, Wr2, br2, xr, NN, CC, HC);
    k_gat<<<(NN+3)/4, 256, 0, stream>>>(xl, xr, csr_src, rowptr, att2, bias2, hraw);
    k_bnstats<<<256, 256, 0, stream>>>(hraw, stats + 256);
    k_bnfin<<<1, 64, 0, stream>>>(stats + 256, stats + 384);
    k_post2<<<(NN*16+255)/256, 256, 0, stream>>>(hraw, hbuf, stats + 384, g2, b2, xres);

    // scores
    k_score<<<(ELI_N*16+255)/256, 256, 0, stream>>>(xres, eli, out);
}

// Round 3
// 457.900 us; speedup vs baseline: 1.4455x; 1.4455x over previous
//
#include <hip/hip_runtime.h>
#include <math.h>

#define NN 50000
#define EE 400000
#define ETOT 450000
#define INC 128
#define CC 64
#define HC 256
#define ELI_N 200000
#define MPAD 50176   // 196*256, padded row count for MFMA A operands

typedef unsigned short u16;
typedef __attribute__((ext_vector_type(8))) short short8v;
typedef __attribute__((ext_vector_type(4))) float f32x4;
typedef __attribute__((ext_vector_type(4))) unsigned short u16x4;

__device__ __forceinline__ u16 f2b(float v){
    unsigned u = __float_as_uint(v);
    u = (u + 0x7fffu + ((u >> 16) & 1u)) >> 16;   // RNE
    return (u16)u;
}
__device__ __forceinline__ float b2f(u16 h){
    return __uint_as_float(((unsigned)h) << 16);
}

// ---------------- CSR build ----------------
__global__ void k_init_deg(int* deg){
    int i = blockIdx.x*256 + threadIdx.x;
    if (i < NN) deg[i] = 1;          // self-loop
}

__global__ void k_count(const int* __restrict__ ei, int* __restrict__ deg){
    int e = blockIdx.x*256 + threadIdx.x;
    if (e < EE) atomicAdd(&deg[ei[EE + e]], 1);
}

__global__ void k_scanA(const int* __restrict__ deg, int* __restrict__ iscan, int* __restrict__ part){
    __shared__ int sh[256];
    int tid = threadIdx.x;
    int base = blockIdx.x*1024 + tid*4;
    int v[4]; int t = 0;
    #pragma unroll
    for (int i = 0; i < 4; i++){ int idx = base + i; v[i] = (idx < NN) ? deg[idx] : 0; t += v[i]; }
    sh[tid] = t; __syncthreads();
    for (int off = 1; off < 256; off <<= 1){
        int u = (tid >= off) ? sh[tid - off] : 0;
        __syncthreads();
        sh[tid] += u;
        __syncthreads();
    }
    int incl = sh[tid];
    int run = incl - t;
    #pragma unroll
    for (int i = 0; i < 4; i++){
        run += v[i];
        int idx = base + i;
        if (idx < NN) iscan[idx] = run;
    }
    if (tid == 255) part[blockIdx.x] = incl;
}

__global__ void k_scanB(int* part, int nb){
    int lane = threadIdx.x & 63;
    int v = (lane < nb) ? part[lane] : 0;
    int orig = v;
    #pragma unroll
    for (int off = 1; off < 64; off <<= 1){
        int u = __shfl_up(v, off, 64);
        if (lane >= off) v += u;
    }
    if (lane < nb) part[lane] = v - orig;   // exclusive
}

__global__ void k_scanC(const int* __restrict__ iscan, const int* __restrict__ part,
                        const int* __restrict__ deg, int* __restrict__ rowptr, int* __restrict__ cursor){
    int i = blockIdx.x*256 + threadIdx.x;
    if (i < NN){
        int v = iscan[i] + part[i >> 10];
        rowptr[i+1] = v;
        cursor[i] = v - deg[i];
    }
    if (i == 0) rowptr[0] = 0;
}

__global__ void k_fill(const int* __restrict__ ei, int* __restrict__ cursor, int* __restrict__ csr_src){
    int idx = blockIdx.x*256 + threadIdx.x;
    if (idx >= ETOT) return;
    int s, d;
    if (idx < EE){ s = ei[idx]; d = ei[EE + idx]; }
    else         { s = idx - EE; d = s; }
    int pos = atomicAdd(&cursor[d], 1);
    csr_src[pos] = s;
}

// ---------------- conversions (hi/lo split for bf16x3) ----------------
__global__ void k_splitX(const float* __restrict__ src, u16* __restrict__ hi, u16* __restrict__ lo){
    int i = blockIdx.x*256 + threadIdx.x;      // float4 index over NN*INC
    if (i >= NN*INC/4) return;
    float4 v = ((const float4*)src)[i];
    float vv[4] = {v.x, v.y, v.z, v.w};
    u16x4 h4, l4;
    #pragma unroll
    for (int j = 0; j < 4; j++){
        u16 h = f2b(vv[j]);
        h4[j] = h;
        l4[j] = f2b(vv[j] - b2f(h));
    }
    *(u16x4*)(hi + (size_t)i*4) = h4;
    *(u16x4*)(lo + (size_t)i*4) = l4;
}

// all 5 weight matrices -> transposed bf16 hi/lo [N][K]
__global__ void k_convW(const float* __restrict__ Wl1, const float* __restrict__ Wr1,
                        const float* __restrict__ Wres, const float* __restrict__ Wl2,
                        const float* __restrict__ Wr2,
                        u16* __restrict__ hl1, u16* __restrict__ ll1,
                        u16* __restrict__ hr1, u16* __restrict__ lr1,
                        u16* __restrict__ hres, u16* __restrict__ lres,
                        u16* __restrict__ hl2, u16* __restrict__ ll2,
                        u16* __restrict__ hr2, u16* __restrict__ lr2){
    int gid = blockIdx.x*256 + threadIdx.x;
    const float* src; u16* dh; u16* dl; int K, N, idx;
    if      (gid <  32768){ src=Wl1;  dh=hl1;  dl=ll1;  K=128; N=256; idx=gid; }
    else if (gid <  65536){ src=Wr1;  dh=hr1;  dl=lr1;  K=128; N=256; idx=gid-32768; }
    else if (gid <  73728){ src=Wres; dh=hres; dl=lres; K=128; N=64;  idx=gid-65536; }
    else if (gid <  90112){ src=Wl2;  dh=hl2;  dl=ll2;  K=64;  N=256; idx=gid-73728; }
    else if (gid < 106496){ src=Wr2;  dh=hr2;  dl=lr2;  K=64;  N=256; idx=gid-90112; }
    else return;
    int k = idx / N, n = idx - k*N;
    float v = src[idx];
    u16 h = f2b(v);
    dh[n*K + k] = h;
    dl[n*K + k] = f2b(v - b2f(h));
}

// ---------------- bf16x3 MFMA GEMM: C[M,N] = A[M,K] @ WT^T + bias (fp32-accurate) --------
// A: bf16 hi/lo row-major [MPAD][K]; WT: bf16 hi/lo [N][K]; wave tile 64x64
template<int KK, int NWM, int NWN>
__global__ __launch_bounds__(256) void k_mgemm(const u16* __restrict__ Ah, const u16* __restrict__ Al,
                                               const u16* __restrict__ Bh, const u16* __restrict__ Bl,
                                               const float* __restrict__ bias, float* __restrict__ Cout,
                                               int M, int N)
{
    int wid = threadIdx.x >> 6, lane = threadIdx.x & 63;
    int wm = wid / NWN, wn = wid % NWN;
    int rm0 = blockIdx.x * (NWM*64) + wm*64;
    int n0  = wn*64;
    int lr = lane & 15;
    int lk = (lane >> 4) << 3;
    f32x4 acc[4][4] = {};
    size_t aoff = (size_t)(rm0 + lr)*KK + lk;
    size_t boff = (size_t)(n0  + lr)*KK + lk;
    #pragma unroll
    for (int ks = 0; ks < KK/32; ks++){
        short8v ah[4], al[4], bh[4], bl[4];
        #pragma unroll
        for (int mf = 0; mf < 4; mf++){
            ah[mf] = *(const short8v*)(Ah + aoff + (size_t)(mf*16)*KK + ks*32);
            al[mf] = *(const short8v*)(Al + aoff + (size_t)(mf*16)*KK + ks*32);
        }
        #pragma unroll
        for (int nf = 0; nf < 4; nf++){
            bh[nf] = *(const short8v*)(Bh + boff + (size_t)(nf*16)*KK + ks*32);
            bl[nf] = *(const short8v*)(Bl + boff + (size_t)(nf*16)*KK + ks*32);
        }
        #pragma unroll
        for (int mf = 0; mf < 4; mf++)
            #pragma unroll
            for (int nf = 0; nf < 4; nf++){
                acc[mf][nf] = __builtin_amdgcn_mfma_f32_16x16x32_bf16(ah[mf], bh[nf], acc[mf][nf], 0, 0, 0);
                acc[mf][nf] = __builtin_amdgcn_mfma_f32_16x16x32_bf16(al[mf], bh[nf], acc[mf][nf], 0, 0, 0);
                acc[mf][nf] = __builtin_amdgcn_mfma_f32_16x16x32_bf16(ah[mf], bl[nf], acc[mf][nf], 0, 0, 0);
            }
    }
    int rbase = (lane >> 4) << 2;
    #pragma unroll
    for (int nf = 0; nf < 4; nf++){
        int col = n0 + nf*16 + lr;
        float bv = bias[col];
        #pragma unroll
        for (int mf = 0; mf < 4; mf++){
            #pragma unroll
            for (int r = 0; r < 4; r++){
                int row = rm0 + mf*16 + rbase + r;
                if (row < M) Cout[(size_t)row*N + col] = acc[mf][nf][r] + bv;
            }
        }
    }
}

// ---------------- fused GATv2 aggregation (fp32, float4 gather, 16-lane reduce) -------------
// wave per node; lane l: head = l>>4, channels (l&15)*4..+3 of the 256-wide row
__global__ __launch_bounds__(256) void k_gat(const float* __restrict__ xl, const float* __restrict__ xr,
                                             const int* __restrict__ csr_src, const int* __restrict__ rowptr,
                                             const float* __restrict__ att, const float* __restrict__ bias,
                                             float* __restrict__ out)
{
    int wave = threadIdx.x >> 6, lane = threadIdx.x & 63;
    int node = blockIdx.x*4 + wave;
    if (node >= NN) return;
    int p0 = rowptr[node], p1 = rowptr[node+1];
    f32x4 xrf  = *(const f32x4*)(xr + (size_t)node*HC + 4*lane);
    f32x4 attf = *(const f32x4*)(att + 4*lane);
    float m = -INFINITY, s = 0.f;
    f32x4 acc = {0.f, 0.f, 0.f, 0.f};
    int p = p0;
    for (; p + 2 <= p1; p += 2){
        int s0 = csr_src[p], s1 = csr_src[p+1];
        f32x4 x0 = *(const f32x4*)(xl + (size_t)s0*HC + 4*lane);
        f32x4 x1 = *(const f32x4*)(xl + (size_t)s1*HC + 4*lane);
        float t0 = 0.f, t1 = 0.f;
        #pragma unroll
        for (int j = 0; j < 4; j++){
            float e0 = x0[j] + xrf[j]; e0 = (e0 > 0.f) ? e0 : 0.2f*e0; t0 += e0*attf[j];
            float e1 = x1[j] + xrf[j]; e1 = (e1 > 0.f) ? e1 : 0.2f*e1; t1 += e1*attf[j];
        }
        #pragma unroll
        for (int off = 1; off < 16; off <<= 1){ t0 += __shfl_xor(t0, off, 64); t1 += __shfl_xor(t1, off, 64); }
        float nm = fmaxf(m, t0); float sc = __expf(m - nm); float w = __expf(t0 - nm);
        s = s*sc + w; acc = acc*sc + x0*w; m = nm;
        nm = fmaxf(m, t1); sc = __expf(m - nm); w = __expf(t1 - nm);
        s = s*sc + w; acc = acc*sc + x1*w; m = nm;
    }
    if (p < p1){
        int s0 = csr_src[p];
        f32x4 x0 = *(const f32x4*)(xl + (size_t)s0*HC + 4*lane);
        float t0 = 0.f;
        #pragma unroll
        for (int j = 0; j < 4; j++){ float e0 = x0[j] + xrf[j]; e0 = (e0 > 0.f) ? e0 : 0.2f*e0; t0 += e0*attf[j]; }
        #pragma unroll
        for (int off = 1; off < 16; off <<= 1) t0 += __shfl_xor(t0, off, 64);
        float nm = fmaxf(m, t0); float sc = __expf(m - nm); float w = __expf(t0 - nm);
        s = s*sc + w; acc = acc*sc + x0*w; m = nm;
    }
    float inv = 1.f / s;
    f32x4 o = acc * inv;
    #pragma unroll
    for (int j = 0; j < 4; j++){ o[j] += __shfl_xor(o[j], 16, 64); o[j] += __shfl_xor(o[j], 32, 64); }
    if (lane < 16){
        f32x4 bv = *(const f32x4*)(bias + 4*lane);
        f32x4 res = o*0.25f + bv;
        *(f32x4*)(out + (size_t)node*CC + 4*lane) = res;
    }
}

// ---------------- BatchNorm ----------------
__global__ __launch_bounds__(256) void k_bnstats(const float* __restrict__ x, float* __restrict__ sums){
    __shared__ float ls[256], lq[256];
    int tid = threadIdx.x; int c = tid & 63; int g = tid >> 6;
    float s = 0.f, q = 0.f;
    for (int r = blockIdx.x*4 + g; r < NN; r += gridDim.x*4){
        float v = x[(size_t)r*64 + c]; s += v; q += v*v;
    }
    ls[tid] = s; lq[tid] = q; __syncthreads();
    if (tid < 64){
        s = ls[tid] + ls[tid+64] + ls[tid+128] + ls[tid+192];
        q = lq[tid] + lq[tid+64] + lq[tid+128] + lq[tid+192];
        atomicAdd(&sums[c], s); atomicAdd(&sums[64 + c], q);
    }
}

__global__ void k_bnfin(const float* __restrict__ sums, float* __restrict__ mr){
    int c = threadIdx.x;
    if (c < 64){
        float mean = sums[c] / (float)NN;
        float var  = sums[64 + c] / (float)NN - mean*mean;
        mr[c] = mean;
        mr[64 + c] = rsqrtf(var + 1e-5f);
    }
}

// h = relu(bn(hraw) + xres); writes fp32 h plus hi/lo bf16 split for layer-2 GEMMs
__global__ void k_post1(const float* __restrict__ hraw, const float* __restrict__ xres,
                        const float* __restrict__ mr, const float* __restrict__ g,
                        const float* __restrict__ b, float* __restrict__ out,
                        u16* __restrict__ hhi, u16* __restrict__ hlo){
    int i = blockIdx.x*256 + threadIdx.x;   // float4 index
    if (i >= NN*16) return;
    float4 hv = ((const float4*)hraw)[i];
    float4 rv = ((const float4*)xres)[i];
    int c0 = (i & 15) * 4;
    float hp[4] = {hv.x, hv.y, hv.z, hv.w};
    float rp[4] = {rv.x, rv.y, rv.z, rv.w};
    float res[4];
    u16x4 h4, l4;
    #pragma unroll
    for (int k = 0; k < 4; k++){
        int c = c0 + k;
        float v = g[c]*(hp[k] - mr[c])*mr[64 + c] + b[c] + rp[k];
        v = (v > 0.f) ? v : 0.f;
        res[k] = v;
        u16 h = f2b(v);
        h4[k] = h;
        l4[k] = f2b(v - b2f(h));
    }
    ((float4*)out)[i] = make_float4(res[0], res[1], res[2], res[3]);
    *(u16x4*)(hhi + (size_t)i*4) = h4;
    *(u16x4*)(hlo + (size_t)i*4) = l4;
}

// z = bn(h2raw) + h
__global__ void k_post2(const float* __restrict__ hraw, const float* __restrict__ hprev,
                        const float* __restrict__ mr, const float* __restrict__ g,
                        const float* __restrict__ b, float* __restrict__ out){
    int i = blockIdx.x*256 + threadIdx.x;
    if (i >= NN*16) return;
    float4 hv = ((const float4*)hraw)[i];
    float4 rv = ((const float4*)hprev)[i];
    int c0 = (i & 15) * 4;
    float hp[4] = {hv.x, hv.y, hv.z, hv.w};
    float rp[4] = {rv.x, rv.y, rv.z, rv.w};
    float res[4];
    #pragma unroll
    for (int k = 0; k < 4; k++){
        int c = c0 + k;
        res[k] = g[c]*(hp[k] - mr[c])*mr[64 + c] + b[c] + rp[k];
    }
    ((float4*)out)[i] = make_float4(res[0], res[1], res[2], res[3]);
}

// ---------------- link-prediction scores ----------------
__global__ __launch_bounds__(256) void k_score(const float* __restrict__ z, const int* __restrict__ eli,
                                               float* __restrict__ out){
    int t = blockIdx.x*256 + threadIdx.x;
    int i = t >> 4; int j = t & 15;
    if (i >= ELI_N) return;
    int a = eli[i], b = eli[ELI_N + i];
    float4 va = ((const float4*)(z + (size_t)a*64))[j];
    float4 vb = ((const float4*)(z + (size_t)b*64))[j];
    float s = va.x*vb.x + va.y*vb.y + va.z*vb.z + va.w*vb.w;
    #pragma unroll
    for (int off = 8; off > 0; off >>= 1) s += __shfl_xor(s, off, 64);
    if (j == 0) out[i] = 1.f / (1.f + __expf(-s));
}

extern "C" void kernel_launch(void* const* d_in, const int* in_sizes, int n_in,
                              void* d_out, int out_size, void* d_ws, size_t ws_size,
                              hipStream_t stream) {
    const float* x    = (const float*)d_in[0];
    const int*   ei   = (const int*)  d_in[1];
    const int*   eli  = (const int*)  d_in[2];
    const float* Wl1  = (const float*)d_in[3];
    const float* bl1  = (const float*)d_in[4];
    const float* Wr1  = (const float*)d_in[5];
    const float* br1  = (const float*)d_in[6];
    const float* att1 = (const float*)d_in[7];
    const float* bias1= (const float*)d_in[8];
    const float* g1   = (const float*)d_in[9];
    const float* b1   = (const float*)d_in[10];
    const float* Wres = (const float*)d_in[11];
    const float* bres = (const float*)d_in[12];
    const float* Wl2  = (const float*)d_in[13];
    const float* bl2  = (const float*)d_in[14];
    const float* Wr2  = (const float*)d_in[15];
    const float* br2  = (const float*)d_in[16];
    const float* att2 = (const float*)d_in[17];
    const float* bias2= (const float*)d_in[18];
    const float* g2   = (const float*)d_in[19];
    const float* b2   = (const float*)d_in[20];
    float* out = (float*)d_out;

    char* w = (char*)d_ws;
    size_t o = 0;
    auto take = [&](size_t bytes)->char*{ char* p = w + o; o += (bytes + 255) & ~(size_t)255; return p; };
    float* xl   = (float*)take((size_t)NN*HC*4);
    float* xr   = (float*)take((size_t)NN*HC*4);
    float* xres = (float*)take((size_t)NN*CC*4);   // later reused as z
    float* hbuf = (float*)take((size_t)NN*CC*4);
    // region A: x_hi for layer-1 GEMMs, then reused as hraw (fp32 GAT output)
    char* regA  = take((size_t)MPAD*INC*2);
    u16*  xhi   = (u16*)regA;
    float* hraw = (float*)regA;                    // NN*CC*4 = 12.80MB <= 12.85MB
    // region B: x_lo for layer-1 GEMMs, then reused as h_hi/h_lo splits
    char* regB  = take((size_t)MPAD*INC*2);
    u16*  xlo   = (u16*)regB;
    u16*  hhi   = (u16*)regB;                      // MPAD*CC*2
    u16*  hlo   = (u16*)(regB + (size_t)MPAD*CC*2);
    u16* whl1 = (u16*)take(256*128*2);  u16* wll1 = (u16*)take(256*128*2);
    u16* whr1 = (u16*)take(256*128*2);  u16* wlr1 = (u16*)take(256*128*2);
    u16* whres= (u16*)take(64*128*2);   u16* wlres= (u16*)take(64*128*2);
    u16* whl2 = (u16*)take(256*64*2);   u16* wll2 = (u16*)take(256*64*2);
    u16* whr2 = (u16*)take(256*64*2);   u16* wlr2 = (u16*)take(256*64*2);
    float* stats= (float*)take(512*4);
    int* deg    = (int*)take((size_t)NN*4);
    int* rowptr = (int*)take((size_t)(NN+1)*4);
    int* iscan  = (int*)take((size_t)NN*4);
    int* cursor = (int*)take((size_t)NN*4);
    int* csr_src= (int*)take((size_t)ETOT*4);
    int* part   = (int*)take(64*4);

    hipMemsetAsync(stats, 0, 512*4, stream);

    // CSR build
    k_init_deg<<<196, 256, 0, stream>>>(deg);
    k_count<<<(EE+255)/256, 256, 0, stream>>>(ei, deg);
    k_scanA<<<49, 256, 0, stream>>>(deg, iscan, part);
    k_scanB<<<1, 64, 0, stream>>>(part, 49);
    k_scanC<<<196, 256, 0, stream>>>(iscan, part, deg, rowptr, cursor);
    k_fill<<<(ETOT+255)/256, 256, 0, stream>>>(ei, cursor, csr_src);

    // conversions
    k_splitX<<<(NN*INC/4+255)/256, 256, 0, stream>>>(x, xhi, xlo);
    k_convW<<<(106496+255)/256, 256, 0, stream>>>(Wl1, Wr1, Wres, Wl2, Wr2,
                                                  whl1, wll1, whr1, wlr1, whres, wlres,
                                                  whl2, wll2, whr2, wlr2);

    // layer 1
    k_mgemm<128,1,4><<<MPAD/64, 256, 0, stream>>>(xhi, xlo, whl1, wll1, bl1, xl, NN, 256);
    k_mgemm<128,1,4><<<MPAD/64, 256, 0, stream>>>(xhi, xlo, whr1, wlr1, br1, xr, NN, 256);
    k_mgemm<128,4,1><<<MPAD/256,256, 0, stream>>>(xhi, xlo, whres, wlres, bres, xres, NN, 64);
    k_gat<<<(NN+3)/4, 256, 0, stream>>>(xl, xr, csr_src, rowptr, att1, bias1, hraw);  // hraw overwrites xhi (done)
    k_bnstats<<<256, 256, 0, stream>>>(hraw, stats);
    k_bnfin<<<1, 64, 0, stream>>>(stats, stats + 128);
    k_post1<<<(NN*16+255)/256, 256, 0, stream>>>(hraw, xres, stats + 128, g1, b1, hbuf, hhi, hlo); // overwrites xlo (done)

    // layer 2
    k_mgemm<64,1,4><<<MPAD/64, 256, 0, stream>>>(hhi, hlo, whl2, wll2, bl2, xl, NN, 256);
    k_mgemm<64,1,4><<<MPAD/64, 256, 0, stream>>>(hhi, hlo, whr2, wlr2, br2, xr, NN, 256);
    k_gat<<<(NN+3)/4, 256, 0, stream>>>(xl, xr, csr_src, rowptr, att2, bias2, hraw);
    k_bnstats<<<256, 256, 0, stream>>>(hraw, stats + 256);
    k_bnfin<<<1, 64, 0, stream>>>(stats + 256, stats + 384);
    k_post2<<<(NN*16+255)/256, 256, 0, stream>>>(hraw, hbuf, stats + 384, g2, b2, xres);

    // scores
    k_score<<<(ELI_N*16+255)/256, 256, 0, stream>>>(xres, eli, out);
}

// Round 4
// 421.036 us; speedup vs baseline: 1.5721x; 1.0876x over previous
//
#include <hip/hip_runtime.h>
#include <math.h>

#define NN 50000
#define EE 400000
#define ETOT 450000
#define INC 128
#define CC 64
#define HC 256
#define ELI_N 200000
#define MPAD 50176   // 784*64

typedef unsigned short u16;
typedef __attribute__((ext_vector_type(8))) short short8v;
typedef __attribute__((ext_vector_type(4))) float f32x4;
typedef __attribute__((ext_vector_type(4))) unsigned short u16x4;

__device__ __forceinline__ u16 f2b(float v){
    unsigned u = __float_as_uint(v);
    u = (u + 0x7fffu + ((u >> 16) & 1u)) >> 16;   // RNE
    return (u16)u;
}
__device__ __forceinline__ float b2f(u16 h){
    return __uint_as_float(((unsigned)h) << 16);
}

// ---------------- CSR build ----------------
__global__ void k_count(const int* __restrict__ ei, int* __restrict__ deg){
    int e = blockIdx.x*256 + threadIdx.x;
    if (e < EE) atomicAdd(&deg[ei[EE + e]], 1);
}

// chunk=1024 per block; deg+1 (self-loop) baked in
__global__ void k_scanA(const int* __restrict__ deg, int* __restrict__ iscan, int* __restrict__ part){
    __shared__ int sh[256];
    int tid = threadIdx.x;
    int base = blockIdx.x*1024 + tid*4;
    int v[4]; int t = 0;
    #pragma unroll
    for (int i = 0; i < 4; i++){ int idx = base + i; v[i] = (idx < NN) ? deg[idx]+1 : 0; t += v[i]; }
    sh[tid] = t; __syncthreads();
    for (int off = 1; off < 256; off <<= 1){
        int u = (tid >= off) ? sh[tid - off] : 0;
        __syncthreads();
        sh[tid] += u;
        __syncthreads();
    }
    int incl = sh[tid];
    int run = incl - t;
    #pragma unroll
    for (int i = 0; i < 4; i++){
        run += v[i];
        int idx = base + i;
        if (idx < NN) iscan[idx] = run;
    }
    if (tid == 255) part[blockIdx.x] = incl;
}

// inline part-prefix (uniform per block: each block lies inside one 1024-chunk)
__global__ void k_scanC(const int* __restrict__ iscan, const int* __restrict__ part,
                        const int* __restrict__ deg, int* __restrict__ rowptr, int* __restrict__ cursor){
    int chunk = blockIdx.x >> 2;
    int ps = 0;
    for (int j = 0; j < chunk; j++) ps += part[j];
    int i = blockIdx.x*256 + threadIdx.x;
    if (i < NN){
        int v = iscan[i] + ps;          // rowptr[i+1]
        rowptr[i+1] = v;
        cursor[i] = v - (deg[i]+1);     // rowptr[i]
    }
    if (i == 0) rowptr[0] = 0;
}

__global__ void k_fill(const int* __restrict__ ei, int* __restrict__ cursor, int* __restrict__ csr_src){
    int idx = blockIdx.x*256 + threadIdx.x;
    if (idx >= ETOT) return;
    int s, d;
    if (idx < EE){ s = ei[idx]; d = ei[EE + idx]; }
    else         { s = idx - EE; d = s; }
    int pos = atomicAdd(&cursor[d], 1);
    csr_src[pos] = s;
}

// ---------------- weights -> transposed bf16 hi/lo [N][K] ----------------
__global__ void k_convW(const float* __restrict__ Wl1, const float* __restrict__ Wr1,
                        const float* __restrict__ Wres, const float* __restrict__ Wl2,
                        const float* __restrict__ Wr2,
                        u16* __restrict__ hl1, u16* __restrict__ ll1,
                        u16* __restrict__ hr1, u16* __restrict__ lr1,
                        u16* __restrict__ hres, u16* __restrict__ lres,
                        u16* __restrict__ hl2, u16* __restrict__ ll2,
                        u16* __restrict__ hr2, u16* __restrict__ lr2){
    int gid = blockIdx.x*256 + threadIdx.x;
    const float* src; u16* dh; u16* dl; int K, N, idx;
    if      (gid <  32768){ src=Wl1;  dh=hl1;  dl=ll1;  K=128; N=256; idx=gid; }
    else if (gid <  65536){ src=Wr1;  dh=hr1;  dl=lr1;  K=128; N=256; idx=gid-32768; }
    else if (gid <  73728){ src=Wres; dh=hres; dl=lres; K=128; N=64;  idx=gid-65536; }
    else if (gid <  90112){ src=Wl2;  dh=hl2;  dl=ll2;  K=64;  N=256; idx=gid-73728; }
    else if (gid < 106496){ src=Wr2;  dh=hr2;  dl=lr2;  K=64;  N=256; idx=gid-90112; }
    else return;
    int k = idx / N, n = idx - k*N;
    float v = src[idx];
    u16 h = f2b(v);
    dh[n*K + k] = h;
    dl[n*K + k] = f2b(v - b2f(h));
}

// ---------------- fused layer-1 GEMM: xl|xr|xres from fp32 x, bf16x3 in-register split ------
__global__ __launch_bounds__(576) void k_gemm1(const float* __restrict__ A,
        const u16* __restrict__ Whl1, const u16* __restrict__ Wll1,
        const u16* __restrict__ Whr1, const u16* __restrict__ Wlr1,
        const u16* __restrict__ Whres,const u16* __restrict__ Wlres,
        const float* __restrict__ bl1, const float* __restrict__ br1, const float* __restrict__ bres,
        float* __restrict__ xl, float* __restrict__ xr, float* __restrict__ xres)
{
    int wid = threadIdx.x >> 6, lane = threadIdx.x & 63;
    const u16 *Bh, *Bl; const float* bias; float* Cout; int n0, N;
    if (wid < 4)      { Bh=Whl1;  Bl=Wll1;  bias=bl1;  Cout=xl;   n0=wid*64;     N=256; }
    else if (wid < 8) { Bh=Whr1;  Bl=Wlr1;  bias=br1;  Cout=xr;   n0=(wid-4)*64; N=256; }
    else              { Bh=Whres; Bl=Wlres; bias=bres; Cout=xres; n0=0;          N=64;  }
    int rm0 = blockIdx.x * 64;
    int lr = lane & 15;
    int lk = (lane >> 4) << 3;
    f32x4 acc[4][4] = {};
    int arow[4];
    #pragma unroll
    for (int mf = 0; mf < 4; mf++){ int r = rm0 + mf*16 + lr; arow[mf] = (r < NN) ? r : NN-1; }
    size_t boff = (size_t)(n0 + lr)*128 + lk;
    #pragma unroll
    for (int ks = 0; ks < 4; ks++){
        short8v ah[4], al[4], bh[4], blo[4];
        #pragma unroll
        for (int mf = 0; mf < 4; mf++){
            const float* ap = A + (size_t)arow[mf]*128 + ks*32 + lk;
            float4 v0 = *(const float4*)ap;
            float4 v1 = *(const float4*)(ap + 4);
            float vv[8] = {v0.x, v0.y, v0.z, v0.w, v1.x, v1.y, v1.z, v1.w};
            #pragma unroll
            for (int j = 0; j < 8; j++){
                u16 h = f2b(vv[j]);
                ah[mf][j] = (short)h;
                al[mf][j] = (short)f2b(vv[j] - b2f(h));
            }
        }
        #pragma unroll
        for (int nf = 0; nf < 4; nf++){
            bh[nf]  = *(const short8v*)(Bh + boff + (size_t)(nf*16)*128 + ks*32);
            blo[nf] = *(const short8v*)(Bl + boff + (size_t)(nf*16)*128 + ks*32);
        }
        #pragma unroll
        for (int mf = 0; mf < 4; mf++)
            #pragma unroll
            for (int nf = 0; nf < 4; nf++){
                acc[mf][nf] = __builtin_amdgcn_mfma_f32_16x16x32_bf16(ah[mf], bh[nf],  acc[mf][nf], 0, 0, 0);
                acc[mf][nf] = __builtin_amdgcn_mfma_f32_16x16x32_bf16(al[mf], bh[nf],  acc[mf][nf], 0, 0, 0);
                acc[mf][nf] = __builtin_amdgcn_mfma_f32_16x16x32_bf16(ah[mf], blo[nf], acc[mf][nf], 0, 0, 0);
            }
    }
    int rbase = (lane >> 4) << 2;
    #pragma unroll
    for (int nf = 0; nf < 4; nf++){
        int col = n0 + nf*16 + lr;
        float bv = bias[col];
        #pragma unroll
        for (int mf = 0; mf < 4; mf++){
            #pragma unroll
            for (int r = 0; r < 4; r++){
                int row = rm0 + mf*16 + rbase + r;
                if (row < NN) Cout[(size_t)row*N + col] = acc[mf][nf][r] + bv;
            }
        }
    }
}

// ---------------- fused layer-2 GEMM: xl|xr from fp32 h, K=64 ----------------
__global__ __launch_bounds__(512) void k_gemm2(const float* __restrict__ A,
        const u16* __restrict__ Whl2, const u16* __restrict__ Wll2,
        const u16* __restrict__ Whr2, const u16* __restrict__ Wlr2,
        const float* __restrict__ bl2, const float* __restrict__ br2,
        float* __restrict__ xl, float* __restrict__ xr)
{
    int wid = threadIdx.x >> 6, lane = threadIdx.x & 63;
    const u16 *Bh, *Bl; const float* bias; float* Cout;
    if (wid < 4){ Bh=Whl2; Bl=Wll2; bias=bl2; Cout=xl; }
    else        { Bh=Whr2; Bl=Wlr2; bias=br2; Cout=xr; }
    int n0 = (wid & 3)*64;
    int rm0 = blockIdx.x * 64;
    int lr = lane & 15;
    int lk = (lane >> 4) << 3;
    f32x4 acc[4][4] = {};
    int arow[4];
    #pragma unroll
    for (int mf = 0; mf < 4; mf++){ int r = rm0 + mf*16 + lr; arow[mf] = (r < NN) ? r : NN-1; }
    size_t boff = (size_t)(n0 + lr)*64 + lk;
    #pragma unroll
    for (int ks = 0; ks < 2; ks++){
        short8v ah[4], al[4], bh[4], blo[4];
        #pragma unroll
        for (int mf = 0; mf < 4; mf++){
            const float* ap = A + (size_t)arow[mf]*64 + ks*32 + lk;
            float4 v0 = *(const float4*)ap;
            float4 v1 = *(const float4*)(ap + 4);
            float vv[8] = {v0.x, v0.y, v0.z, v0.w, v1.x, v1.y, v1.z, v1.w};
            #pragma unroll
            for (int j = 0; j < 8; j++){
                u16 h = f2b(vv[j]);
                ah[mf][j] = (short)h;
                al[mf][j] = (short)f2b(vv[j] - b2f(h));
            }
        }
        #pragma unroll
        for (int nf = 0; nf < 4; nf++){
            bh[nf]  = *(const short8v*)(Bh + boff + (size_t)(nf*16)*64 + ks*32);
            blo[nf] = *(const short8v*)(Bl + boff + (size_t)(nf*16)*64 + ks*32);
        }
        #pragma unroll
        for (int mf = 0; mf < 4; mf++)
            #pragma unroll
            for (int nf = 0; nf < 4; nf++){
                acc[mf][nf] = __builtin_amdgcn_mfma_f32_16x16x32_bf16(ah[mf], bh[nf],  acc[mf][nf], 0, 0, 0);
                acc[mf][nf] = __builtin_amdgcn_mfma_f32_16x16x32_bf16(al[mf], bh[nf],  acc[mf][nf], 0, 0, 0);
                acc[mf][nf] = __builtin_amdgcn_mfma_f32_16x16x32_bf16(ah[mf], blo[nf], acc[mf][nf], 0, 0, 0);
            }
    }
    int rbase = (lane >> 4) << 2;
    #pragma unroll
    for (int nf = 0; nf < 4; nf++){
        int col = n0 + nf*16 + lr;
        float bv = bias[col];
        #pragma unroll
        for (int mf = 0; mf < 4; mf++){
            #pragma unroll
            for (int r = 0; r < 4; r++){
                int row = rm0 + mf*16 + rbase + r;
                if (row < NN) Cout[(size_t)row*256 + col] = acc[mf][nf][r] + bv;
            }
        }
    }
}

// ---------------- fused GATv2 aggregation (no-max softmax, unroll-4) -------------
// wave per node; lane l covers channels 4l..4l+3 of 256-wide row; head = l>>4
__global__ __launch_bounds__(256) void k_gat(const float* __restrict__ xl, const float* __restrict__ xr,
                                             const int* __restrict__ csr_src, const int* __restrict__ rowptr,
                                             const float* __restrict__ att, const float* __restrict__ bias,
                                             float* __restrict__ out)
{
    int wave = threadIdx.x >> 6, lane = threadIdx.x & 63;
    int node = blockIdx.x*4 + wave;
    if (node >= NN) return;
    int p0 = rowptr[node], p1 = rowptr[node+1];
    f32x4 xrf  = *(const f32x4*)(xr + (size_t)node*HC + 4*lane);
    f32x4 attf = *(const f32x4*)(att + 4*lane);
    float s = 0.f;
    f32x4 acc = {0.f, 0.f, 0.f, 0.f};
    int p = p0;
    for (; p + 4 <= p1; p += 4){
        int i0 = csr_src[p], i1 = csr_src[p+1], i2 = csr_src[p+2], i3 = csr_src[p+3];
        f32x4 x0 = *(const f32x4*)(xl + (size_t)i0*HC + 4*lane);
        f32x4 x1 = *(const f32x4*)(xl + (size_t)i1*HC + 4*lane);
        f32x4 x2 = *(const f32x4*)(xl + (size_t)i2*HC + 4*lane);
        f32x4 x3 = *(const f32x4*)(xl + (size_t)i3*HC + 4*lane);
        float t0 = 0.f, t1 = 0.f, t2 = 0.f, t3 = 0.f;
        #pragma unroll
        for (int j = 0; j < 4; j++){
            float e0 = x0[j] + xrf[j]; e0 = (e0 > 0.f) ? e0 : 0.2f*e0; t0 += e0*attf[j];
            float e1 = x1[j] + xrf[j]; e1 = (e1 > 0.f) ? e1 : 0.2f*e1; t1 += e1*attf[j];
            float e2 = x2[j] + xrf[j]; e2 = (e2 > 0.f) ? e2 : 0.2f*e2; t2 += e2*attf[j];
            float e3 = x3[j] + xrf[j]; e3 = (e3 > 0.f) ? e3 : 0.2f*e3; t3 += e3*attf[j];
        }
        #pragma unroll
        for (int off = 1; off < 16; off <<= 1){
            t0 += __shfl_xor(t0, off, 64);
            t1 += __shfl_xor(t1, off, 64);
            t2 += __shfl_xor(t2, off, 64);
            t3 += __shfl_xor(t3, off, 64);
        }
        float w0 = __expf(t0), w1 = __expf(t1), w2 = __expf(t2), w3 = __expf(t3);
        s += (w0 + w1) + (w2 + w3);
        acc = acc + x0*w0 + x1*w1 + x2*w2 + x3*w3;
    }
    for (; p < p1; p++){
        int i0 = csr_src[p];
        f32x4 x0 = *(const f32x4*)(xl + (size_t)i0*HC + 4*lane);
        float t0 = 0.f;
        #pragma unroll
        for (int j = 0; j < 4; j++){ float e0 = x0[j] + xrf[j]; e0 = (e0 > 0.f) ? e0 : 0.2f*e0; t0 += e0*attf[j]; }
        #pragma unroll
        for (int off = 1; off < 16; off <<= 1) t0 += __shfl_xor(t0, off, 64);
        float w0 = __expf(t0);
        s += w0;
        acc = acc + x0*w0;
    }
    float inv = 1.f / s;          // s uniform within each 16-lane head group
    f32x4 o = acc * inv;
    #pragma unroll
    for (int j = 0; j < 4; j++){ o[j] += __shfl_xor(o[j], 16, 64); o[j] += __shfl_xor(o[j], 32, 64); }
    if (lane < 16){
        f32x4 bv = *(const f32x4*)(bias + 4*lane);
        f32x4 res = o*0.25f + bv;
        *(f32x4*)(out + (size_t)node*CC + 4*lane) = res;
    }
}

// ---------------- BatchNorm stats ----------------
__global__ __launch_bounds__(256) void k_bnstats(const float* __restrict__ x, float* __restrict__ sums){
    __shared__ float ls[256], lq[256];
    int tid = threadIdx.x; int c = tid & 63; int g = tid >> 6;
    float s = 0.f, q = 0.f;
    for (int r = blockIdx.x*4 + g; r < NN; r += gridDim.x*4){
        float v = x[(size_t)r*64 + c]; s += v; q += v*v;
    }
    ls[tid] = s; lq[tid] = q; __syncthreads();
    if (tid < 64){
        s = ls[tid] + ls[tid+64] + ls[tid+128] + ls[tid+192];
        q = lq[tid] + lq[tid+64] + lq[tid+128] + lq[tid+192];
        atomicAdd(&sums[c], s); atomicAdd(&sums[64 + c], q);
    }
}

// h = relu(bn(hraw) + xres)  (mean/rstd from raw sums, inline)
__global__ void k_post1(const float* __restrict__ hraw, const float* __restrict__ xres,
                        const float* __restrict__ sums, const float* __restrict__ g,
                        const float* __restrict__ b, float* __restrict__ out){
    int i = blockIdx.x*256 + threadIdx.x;   // float4 index
    if (i >= NN*16) return;
    float4 hv = ((const float4*)hraw)[i];
    float4 rv = ((const float4*)xres)[i];
    int c0 = (i & 15) * 4;
    float hp[4] = {hv.x, hv.y, hv.z, hv.w};
    float rp[4] = {rv.x, rv.y, rv.z, rv.w};
    float res[4];
    const float invN = 1.f / (float)NN;
    #pragma unroll
    for (int k = 0; k < 4; k++){
        int c = c0 + k;
        float mean = sums[c] * invN;
        float var  = sums[64 + c] * invN - mean*mean;
        float rstd = rsqrtf(var + 1e-5f);
        float v = g[c]*(hp[k] - mean)*rstd + b[c] + rp[k];
        res[k] = (v > 0.f) ? v : 0.f;
    }
    ((float4*)out)[i] = make_float4(res[0], res[1], res[2], res[3]);
}

// z = bn(h2raw) + h
__global__ void k_post2(const float* __restrict__ hraw, const float* __restrict__ hprev,
                        const float* __restrict__ sums, const float* __restrict__ g,
                        const float* __restrict__ b, float* __restrict__ out){
    int i = blockIdx.x*256 + threadIdx.x;
    if (i >= NN*16) return;
    float4 hv = ((const float4*)hraw)[i];
    float4 rv = ((const float4*)hprev)[i];
    int c0 = (i & 15) * 4;
    float hp[4] = {hv.x, hv.y, hv.z, hv.w};
    float rp[4] = {rv.x, rv.y, rv.z, rv.w};
    float res[4];
    const float invN = 1.f / (float)NN;
    #pragma unroll
    for (int k = 0; k < 4; k++){
        int c = c0 + k;
        float mean = sums[c] * invN;
        float var  = sums[64 + c] * invN - mean*mean;
        float rstd = rsqrtf(var + 1e-5f);
        res[k] = g[c]*(hp[k] - mean)*rstd + b[c] + rp[k];
    }
    ((float4*)out)[i] = make_float4(res[0], res[1], res[2], res[3]);
}

// ---------------- link-prediction scores ----------------
__global__ __launch_bounds__(256) void k_score(const float* __restrict__ z, const int* __restrict__ eli,
                                               float* __restrict__ out){
    int t = blockIdx.x*256 + threadIdx.x;
    int i = t >> 4; int j = t & 15;
    if (i >= ELI_N) return;
    int a = eli[i], b = eli[ELI_N + i];
    float4 va = ((const float4*)(z + (size_t)a*64))[j];
    float4 vb = ((const float4*)(z + (size_t)b*64))[j];
    float s = va.x*vb.x + va.y*vb.y + va.z*vb.z + va.w*vb.w;
    #pragma unroll
    for (int off = 8; off > 0; off >>= 1) s += __shfl_xor(s, off, 64);
    if (j == 0) out[i] = 1.f / (1.f + __expf(-s));
}

extern "C" void kernel_launch(void* const* d_in, const int* in_sizes, int n_in,
                              void* d_out, int out_size, void* d_ws, size_t ws_size,
                              hipStream_t stream) {
    const float* x    = (const float*)d_in[0];
    const int*   ei   = (const int*)  d_in[1];
    const int*   eli  = (const int*)  d_in[2];
    const float* Wl1  = (const float*)d_in[3];
    const float* bl1  = (const float*)d_in[4];
    const float* Wr1  = (const float*)d_in[5];
    const float* br1  = (const float*)d_in[6];
    const float* att1 = (const float*)d_in[7];
    const float* bias1= (const float*)d_in[8];
    const float* g1   = (const float*)d_in[9];
    const float* b1   = (const float*)d_in[10];
    const float* Wres = (const float*)d_in[11];
    const float* bres = (const float*)d_in[12];
    const float* Wl2  = (const float*)d_in[13];
    const float* bl2  = (const float*)d_in[14];
    const float* Wr2  = (const float*)d_in[15];
    const float* br2  = (const float*)d_in[16];
    const float* att2 = (const float*)d_in[17];
    const float* bias2= (const float*)d_in[18];
    const float* g2   = (const float*)d_in[19];
    const float* b2   = (const float*)d_in[20];
    float* out = (float*)d_out;

    char* w = (char*)d_ws;
    size_t o = 0;
    auto take = [&](size_t bytes)->char*{ char* p = w + o; o += (bytes + 255) & ~(size_t)255; return p; };
    float* xl   = (float*)take((size_t)NN*HC*4);
    float* xr   = (float*)take((size_t)NN*HC*4);
    float* xres = (float*)take((size_t)NN*CC*4);   // later reused as z
    float* hraw = (float*)take((size_t)NN*CC*4);
    float* hbuf = (float*)take((size_t)NN*CC*4);
    u16* whl1 = (u16*)take(256*128*2);  u16* wll1 = (u16*)take(256*128*2);
    u16* whr1 = (u16*)take(256*128*2);  u16* wlr1 = (u16*)take(256*128*2);
    u16* whres= (u16*)take(64*128*2);   u16* wlres= (u16*)take(64*128*2);
    u16* whl2 = (u16*)take(256*64*2);   u16* wll2 = (u16*)take(256*64*2);
    u16* whr2 = (u16*)take(256*64*2);   u16* wlr2 = (u16*)take(256*64*2);
    // stats (256 floats) + deg (NN ints), contiguous for a single memset
    char* zreg  = take(256*4 + (size_t)NN*4);
    float* stats= (float*)zreg;
    int* deg    = (int*)(zreg + 256*4);
    int* rowptr = (int*)take((size_t)(NN+1)*4);
    int* iscan  = (int*)take((size_t)NN*4);
    int* cursor = (int*)take((size_t)NN*4);
    int* csr_src= (int*)take((size_t)ETOT*4);
    int* part   = (int*)take(64*4);

    hipMemsetAsync(zreg, 0, 256*4 + (size_t)NN*4, stream);

    // CSR build
    k_count<<<(EE+255)/256, 256, 0, stream>>>(ei, deg);
    k_scanA<<<49, 256, 0, stream>>>(deg, iscan, part);
    k_scanC<<<196, 256, 0, stream>>>(iscan, part, deg, rowptr, cursor);
    k_fill<<<(ETOT+255)/256, 256, 0, stream>>>(ei, cursor, csr_src);

    // weights
    k_convW<<<(106496+255)/256, 256, 0, stream>>>(Wl1, Wr1, Wres, Wl2, Wr2,
                                                  whl1, wll1, whr1, wlr1, whres, wlres,
                                                  whl2, wll2, whr2, wlr2);

    // layer 1
    k_gemm1<<<MPAD/64, 576, 0, stream>>>(x, whl1, wll1, whr1, wlr1, whres, wlres,
                                         bl1, br1, bres, xl, xr, xres);
    k_gat<<<(NN+3)/4, 256, 0, stream>>>(xl, xr, csr_src, rowptr, att1, bias1, hraw);
    k_bnstats<<<256, 256, 0, stream>>>(hraw, stats);
    k_post1<<<(NN*16+255)/256, 256, 0, stream>>>(hraw, xres, stats, g1, b1, hbuf);

    // layer 2
    k_gemm2<<<MPAD/64, 512, 0, stream>>>(hbuf, whl2, wll2, whr2, wlr2, bl2, br2, xl, xr);
    k_gat<<<(NN+3)/4, 256, 0, stream>>>(xl, xr, csr_src, rowptr, att2, bias2, hraw);
    k_bnstats<<<256, 256, 0, stream>>>(hraw, stats + 128);
    k_post2<<<(NN*16+255)/256, 256, 0, stream>>>(hraw, hbuf, stats + 128, g2, b2, xres);

    // scores
    k_score<<<(ELI_N*16+255)/256, 256, 0, stream>>>(xres, eli, out);
}

// Round 5
// 410.575 us; speedup vs baseline: 1.6122x; 1.0255x over previous
//
#include <hip/hip_runtime.h>
#include <math.h>

#define NN 50000
#define EE 400000
#define ETOT 450000
#define INC 128
#define CC 64
#define HC 256
#define ELI_N 200000
#define MPAD 50176   // 784*64 = 196*256

typedef unsigned short u16;
typedef __attribute__((ext_vector_type(8))) short short8v;
typedef __attribute__((ext_vector_type(4))) float f32x4;
typedef __attribute__((ext_vector_type(4))) unsigned short u16x4;

__device__ __forceinline__ u16 f2b(float v){
    unsigned u = __float_as_uint(v);
    u = (u + 0x7fffu + ((u >> 16) & 1u)) >> 16;   // RNE
    return (u16)u;
}
__device__ __forceinline__ float b2f(u16 h){
    return __uint_as_float(((unsigned)h) << 16);
}

// ---------------- CSR build ----------------
__global__ void k_count(const int* __restrict__ ei, int* __restrict__ deg){
    int e = blockIdx.x*256 + threadIdx.x;
    if (e < EE) atomicAdd(&deg[ei[EE + e]], 1);
}

// chunk=1024 per block; deg+1 (self-loop) baked in
__global__ void k_scanA(const int* __restrict__ deg, int* __restrict__ iscan, int* __restrict__ part){
    __shared__ int sh[256];
    int tid = threadIdx.x;
    int base = blockIdx.x*1024 + tid*4;
    int v[4]; int t = 0;
    #pragma unroll
    for (int i = 0; i < 4; i++){ int idx = base + i; v[i] = (idx < NN) ? deg[idx]+1 : 0; t += v[i]; }
    sh[tid] = t; __syncthreads();
    for (int off = 1; off < 256; off <<= 1){
        int u = (tid >= off) ? sh[tid - off] : 0;
        __syncthreads();
        sh[tid] += u;
        __syncthreads();
    }
    int incl = sh[tid];
    int run = incl - t;
    #pragma unroll
    for (int i = 0; i < 4; i++){
        run += v[i];
        int idx = base + i;
        if (idx < NN) iscan[idx] = run;
    }
    if (tid == 255) part[blockIdx.x] = incl;
}

// inline part-prefix (uniform per block: each block lies inside one 1024-chunk)
__global__ void k_scanC(const int* __restrict__ iscan, const int* __restrict__ part,
                        const int* __restrict__ deg, int* __restrict__ rowptr, int* __restrict__ cursor){
    int chunk = blockIdx.x >> 2;
    int ps = 0;
    for (int j = 0; j < chunk; j++) ps += part[j];
    int i = blockIdx.x*256 + threadIdx.x;
    if (i < NN){
        int v = iscan[i] + ps;          // rowptr[i+1]
        rowptr[i+1] = v;
        cursor[i] = v - (deg[i]+1);     // rowptr[i]
    }
    if (i == 0) rowptr[0] = 0;
}

__global__ void k_fill(const int* __restrict__ ei, int* __restrict__ cursor, int* __restrict__ csr_src){
    int idx = blockIdx.x*256 + threadIdx.x;
    if (idx >= ETOT) return;
    int s, d;
    if (idx < EE){ s = ei[idx]; d = ei[EE + idx]; }
    else         { s = idx - EE; d = s; }
    int pos = atomicAdd(&cursor[d], 1);
    csr_src[pos] = s;
}

// ---------------- weights -> transposed bf16 hi/lo [N][K] ----------------
__global__ void k_convW(const float* __restrict__ Wl1, const float* __restrict__ Wr1,
                        const float* __restrict__ Wres, const float* __restrict__ Wl2,
                        const float* __restrict__ Wr2,
                        u16* __restrict__ hl1, u16* __restrict__ ll1,
                        u16* __restrict__ hr1, u16* __restrict__ lr1,
                        u16* __restrict__ hres, u16* __restrict__ lres,
                        u16* __restrict__ hl2, u16* __restrict__ ll2,
                        u16* __restrict__ hr2, u16* __restrict__ lr2){
    int gid = blockIdx.x*256 + threadIdx.x;
    const float* src; u16* dh; u16* dl; int K, N, idx;
    if      (gid <  32768){ src=Wl1;  dh=hl1;  dl=ll1;  K=128; N=256; idx=gid; }
    else if (gid <  65536){ src=Wr1;  dh=hr1;  dl=lr1;  K=128; N=256; idx=gid-32768; }
    else if (gid <  73728){ src=Wres; dh=hres; dl=lres; K=128; N=64;  idx=gid-65536; }
    else if (gid <  90112){ src=Wl2;  dh=hl2;  dl=ll2;  K=64;  N=256; idx=gid-73728; }
    else if (gid < 106496){ src=Wr2;  dh=hr2;  dl=lr2;  K=64;  N=256; idx=gid-90112; }
    else return;
    int k = idx / N, n = idx - k*N;
    float v = src[idx];
    u16 h = f2b(v);
    dh[n*K + k] = h;
    dl[n*K + k] = f2b(v - b2f(h));
}

// ---------------- fused layer-1 GEMM: xl|xr|xres from fp32 x, bf16x3 in-register split ------
// grid (196, 9): blockIdx.y = column tile (0-3: xl, 4-7: xr, 8: xres); 4 waves = 4 row-blocks
__global__ __launch_bounds__(256) void k_gemm1(const float* __restrict__ A,
        const u16* __restrict__ Whl1, const u16* __restrict__ Wll1,
        const u16* __restrict__ Whr1, const u16* __restrict__ Wlr1,
        const u16* __restrict__ Whres,const u16* __restrict__ Wlres,
        const float* __restrict__ bl1, const float* __restrict__ br1, const float* __restrict__ bres,
        float* __restrict__ xl, float* __restrict__ xr, float* __restrict__ xres)
{
    int wid = threadIdx.x >> 6, lane = threadIdx.x & 63;
    int tile = blockIdx.y;
    const u16 *Bh, *Bl; const float* bias; float* Cout; int n0, N;
    if (tile < 4)      { Bh=Whl1;  Bl=Wll1;  bias=bl1;  Cout=xl;   n0=tile*64;     N=256; }
    else if (tile < 8) { Bh=Whr1;  Bl=Wlr1;  bias=br1;  Cout=xr;   n0=(tile-4)*64; N=256; }
    else               { Bh=Whres; Bl=Wlres; bias=bres; Cout=xres; n0=0;           N=64;  }
    int rm0 = (blockIdx.x*4 + wid) * 64;
    int lr = lane & 15;
    int lk = (lane >> 4) << 3;
    f32x4 acc[4][4] = {};
    int arow[4];
    #pragma unroll
    for (int mf = 0; mf < 4; mf++){ int r = rm0 + mf*16 + lr; arow[mf] = (r < NN) ? r : NN-1; }
    size_t boff = (size_t)(n0 + lr)*128 + lk;
    #pragma unroll
    for (int ks = 0; ks < 4; ks++){
        short8v ah[4], al[4], bh[4], blo[4];
        #pragma unroll
        for (int mf = 0; mf < 4; mf++){
            const float* ap = A + (size_t)arow[mf]*128 + ks*32 + lk;
            float4 v0 = *(const float4*)ap;
            float4 v1 = *(const float4*)(ap + 4);
            float vv[8] = {v0.x, v0.y, v0.z, v0.w, v1.x, v1.y, v1.z, v1.w};
            #pragma unroll
            for (int j = 0; j < 8; j++){
                u16 h = f2b(vv[j]);
                ah[mf][j] = (short)h;
                al[mf][j] = (short)f2b(vv[j] - b2f(h));
            }
        }
        #pragma unroll
        for (int nf = 0; nf < 4; nf++){
            bh[nf]  = *(const short8v*)(Bh + boff + (size_t)(nf*16)*128 + ks*32);
            blo[nf] = *(const short8v*)(Bl + boff + (size_t)(nf*16)*128 + ks*32);
        }
        #pragma unroll
        for (int mf = 0; mf < 4; mf++)
            #pragma unroll
            for (int nf = 0; nf < 4; nf++){
                acc[mf][nf] = __builtin_amdgcn_mfma_f32_16x16x32_bf16(ah[mf], bh[nf],  acc[mf][nf], 0, 0, 0);
                acc[mf][nf] = __builtin_amdgcn_mfma_f32_16x16x32_bf16(al[mf], bh[nf],  acc[mf][nf], 0, 0, 0);
                acc[mf][nf] = __builtin_amdgcn_mfma_f32_16x16x32_bf16(ah[mf], blo[nf], acc[mf][nf], 0, 0, 0);
            }
    }
    int rbase = (lane >> 4) << 2;
    #pragma unroll
    for (int nf = 0; nf < 4; nf++){
        int col = n0 + nf*16 + lr;
        float bv = bias[col];
        #pragma unroll
        for (int mf = 0; mf < 4; mf++){
            #pragma unroll
            for (int r = 0; r < 4; r++){
                int row = rm0 + mf*16 + rbase + r;
                if (row < NN) Cout[(size_t)row*N + col] = acc[mf][nf][r] + bv;
            }
        }
    }
}

// ---------------- fused layer-2 GEMM: xl|xr from fp32 h, K=64 ----------------
// grid (196, 8): blockIdx.y = column tile (0-3: xl, 4-7: xr); 4 waves = 4 row-blocks
__global__ __launch_bounds__(256) void k_gemm2(const float* __restrict__ A,
        const u16* __restrict__ Whl2, const u16* __restrict__ Wll2,
        const u16* __restrict__ Whr2, const u16* __restrict__ Wlr2,
        const float* __restrict__ bl2, const float* __restrict__ br2,
        float* __restrict__ xl, float* __restrict__ xr)
{
    int wid = threadIdx.x >> 6, lane = threadIdx.x & 63;
    int tile = blockIdx.y;
    const u16 *Bh, *Bl; const float* bias; float* Cout;
    if (tile < 4){ Bh=Whl2; Bl=Wll2; bias=bl2; Cout=xl; }
    else         { Bh=Whr2; Bl=Wlr2; bias=br2; Cout=xr; }
    int n0 = (tile & 3)*64;
    int rm0 = (blockIdx.x*4 + wid) * 64;
    int lr = lane & 15;
    int lk = (lane >> 4) << 3;
    f32x4 acc[4][4] = {};
    int arow[4];
    #pragma unroll
    for (int mf = 0; mf < 4; mf++){ int r = rm0 + mf*16 + lr; arow[mf] = (r < NN) ? r : NN-1; }
    size_t boff = (size_t)(n0 + lr)*64 + lk;
    #pragma unroll
    for (int ks = 0; ks < 2; ks++){
        short8v ah[4], al[4], bh[4], blo[4];
        #pragma unroll
        for (int mf = 0; mf < 4; mf++){
            const float* ap = A + (size_t)arow[mf]*64 + ks*32 + lk;
            float4 v0 = *(const float4*)ap;
            float4 v1 = *(const float4*)(ap + 4);
            float vv[8] = {v0.x, v0.y, v0.z, v0.w, v1.x, v1.y, v1.z, v1.w};
            #pragma unroll
            for (int j = 0; j < 8; j++){
                u16 h = f2b(vv[j]);
                ah[mf][j] = (short)h;
                al[mf][j] = (short)f2b(vv[j] - b2f(h));
            }
        }
        #pragma unroll
        for (int nf = 0; nf < 4; nf++){
            bh[nf]  = *(const short8v*)(Bh + boff + (size_t)(nf*16)*64 + ks*32);
            blo[nf] = *(const short8v*)(Bl + boff + (size_t)(nf*16)*64 + ks*32);
        }
        #pragma unroll
        for (int mf = 0; mf < 4; mf++)
            #pragma unroll
            for (int nf = 0; nf < 4; nf++){
                acc[mf][nf] = __builtin_amdgcn_mfma_f32_16x16x32_bf16(ah[mf], bh[nf],  acc[mf][nf], 0, 0, 0);
                acc[mf][nf] = __builtin_amdgcn_mfma_f32_16x16x32_bf16(al[mf], bh[nf],  acc[mf][nf], 0, 0, 0);
                acc[mf][nf] = __builtin_amdgcn_mfma_f32_16x16x32_bf16(ah[mf], blo[nf], acc[mf][nf], 0, 0, 0);
            }
    }
    int rbase = (lane >> 4) << 2;
    #pragma unroll
    for (int nf = 0; nf < 4; nf++){
        int col = n0 + nf*16 + lr;
        float bv = bias[col];
        #pragma unroll
        for (int mf = 0; mf < 4; mf++){
            #pragma unroll
            for (int r = 0; r < 4; r++){
                int row = rm0 + mf*16 + rbase + r;
                if (row < NN) Cout[(size_t)row*256 + col] = acc[mf][nf][r] + bv;
            }
        }
    }
}

// ---------------- fused GATv2 aggregation (no-max softmax, unroll-4) -------------
// wave per node; lane l covers channels 4l..4l+3 of 256-wide row; head = l>>4
__global__ __launch_bounds__(256) void k_gat(const float* __restrict__ xl, const float* __restrict__ xr,
                                             const int* __restrict__ csr_src, const int* __restrict__ rowptr,
                                             const float* __restrict__ att, const float* __restrict__ bias,
                                             float* __restrict__ out)
{
    int wave = threadIdx.x >> 6, lane = threadIdx.x & 63;
    int node = blockIdx.x*4 + wave;
    if (node >= NN) return;
    int p0 = rowptr[node], p1 = rowptr[node+1];
    f32x4 xrf  = *(const f32x4*)(xr + (size_t)node*HC + 4*lane);
    f32x4 attf = *(const f32x4*)(att + 4*lane);
    float s = 0.f;
    f32x4 acc = {0.f, 0.f, 0.f, 0.f};
    int p = p0;
    for (; p + 4 <= p1; p += 4){
        int i0 = csr_src[p], i1 = csr_src[p+1], i2 = csr_src[p+2], i3 = csr_src[p+3];
        f32x4 x0 = *(const f32x4*)(xl + (size_t)i0*HC + 4*lane);
        f32x4 x1 = *(const f32x4*)(xl + (size_t)i1*HC + 4*lane);
        f32x4 x2 = *(const f32x4*)(xl + (size_t)i2*HC + 4*lane);
        f32x4 x3 = *(const f32x4*)(xl + (size_t)i3*HC + 4*lane);
        float t0 = 0.f, t1 = 0.f, t2 = 0.f, t3 = 0.f;
        #pragma unroll
        for (int j = 0; j < 4; j++){
            float e0 = x0[j] + xrf[j]; e0 = (e0 > 0.f) ? e0 : 0.2f*e0; t0 += e0*attf[j];
            float e1 = x1[j] + xrf[j]; e1 = (e1 > 0.f) ? e1 : 0.2f*e1; t1 += e1*attf[j];
            float e2 = x2[j] + xrf[j]; e2 = (e2 > 0.f) ? e2 : 0.2f*e2; t2 += e2*attf[j];
            float e3 = x3[j] + xrf[j]; e3 = (e3 > 0.f) ? e3 : 0.2f*e3; t3 += e3*attf[j];
        }
        #pragma unroll
        for (int off = 1; off < 16; off <<= 1){
            t0 += __shfl_xor(t0, off, 64);
            t1 += __shfl_xor(t1, off, 64);
            t2 += __shfl_xor(t2, off, 64);
            t3 += __shfl_xor(t3, off, 64);
        }
        float w0 = __expf(t0), w1 = __expf(t1), w2 = __expf(t2), w3 = __expf(t3);
        s += (w0 + w1) + (w2 + w3);
        acc = acc + x0*w0 + x1*w1 + x2*w2 + x3*w3;
    }
    for (; p < p1; p++){
        int i0 = csr_src[p];
        f32x4 x0 = *(const f32x4*)(xl + (size_t)i0*HC + 4*lane);
        float t0 = 0.f;
        #pragma unroll
        for (int j = 0; j < 4; j++){ float e0 = x0[j] + xrf[j]; e0 = (e0 > 0.f) ? e0 : 0.2f*e0; t0 += e0*attf[j]; }
        #pragma unroll
        for (int off = 1; off < 16; off <<= 1) t0 += __shfl_xor(t0, off, 64);
        float w0 = __expf(t0);
        s += w0;
        acc = acc + x0*w0;
    }
    float inv = 1.f / s;          // s uniform within each 16-lane head group
    f32x4 o = acc * inv;
    #pragma unroll
    for (int j = 0; j < 4; j++){ o[j] += __shfl_xor(o[j], 16, 64); o[j] += __shfl_xor(o[j], 32, 64); }
    if (lane < 16){
        f32x4 bv = *(const f32x4*)(bias + 4*lane);
        f32x4 res = o*0.25f + bv;
        *(f32x4*)(out + (size_t)node*CC + 4*lane) = res;
    }
}

// ---------------- BatchNorm stats ----------------
__global__ __launch_bounds__(256) void k_bnstats(const float* __restrict__ x, float* __restrict__ sums){
    __shared__ float ls[256], lq[256];
    int tid = threadIdx.x; int c = tid & 63; int g = tid >> 6;
    float s = 0.f, q = 0.f;
    for (int r = blockIdx.x*4 + g; r < NN; r += gridDim.x*4){
        float v = x[(size_t)r*64 + c]; s += v; q += v*v;
    }
    ls[tid] = s; lq[tid] = q; __syncthreads();
    if (tid < 64){
        s = ls[tid] + ls[tid+64] + ls[tid+128] + ls[tid+192];
        q = lq[tid] + lq[tid+64] + lq[tid+128] + lq[tid+192];
        atomicAdd(&sums[c], s); atomicAdd(&sums[64 + c], q);
    }
}

// h = relu(bn(hraw) + xres)  (mean/rstd from raw sums, inline)
__global__ void k_post1(const float* __restrict__ hraw, const float* __restrict__ xres,
                        const float* __restrict__ sums, const float* __restrict__ g,
                        const float* __restrict__ b, float* __restrict__ out){
    int i = blockIdx.x*256 + threadIdx.x;   // float4 index
    if (i >= NN*16) return;
    float4 hv = ((const float4*)hraw)[i];
    float4 rv = ((const float4*)xres)[i];
    int c0 = (i & 15) * 4;
    float hp[4] = {hv.x, hv.y, hv.z, hv.w};
    float rp[4] = {rv.x, rv.y, rv.z, rv.w};
    float res[4];
    const float invN = 1.f / (float)NN;
    #pragma unroll
    for (int k = 0; k < 4; k++){
        int c = c0 + k;
        float mean = sums[c] * invN;
        float var  = sums[64 + c] * invN - mean*mean;
        float rstd = rsqrtf(var + 1e-5f);
        float v = g[c]*(hp[k] - mean)*rstd + b[c] + rp[k];
        res[k] = (v > 0.f) ? v : 0.f;
    }
    ((float4*)out)[i] = make_float4(res[0], res[1], res[2], res[3]);
}

// z = bn(h2raw) + h
__global__ void k_post2(const float* __restrict__ hraw, const float* __restrict__ hprev,
                        const float* __restrict__ sums, const float* __restrict__ g,
                        const float* __restrict__ b, float* __restrict__ out){
    int i = blockIdx.x*256 + threadIdx.x;
    if (i >= NN*16) return;
    float4 hv = ((const float4*)hraw)[i];
    float4 rv = ((const float4*)hprev)[i];
    int c0 = (i & 15) * 4;
    float hp[4] = {hv.x, hv.y, hv.z, hv.w};
    float rp[4] = {rv.x, rv.y, rv.z, rv.w};
    float res[4];
    const float invN = 1.f / (float)NN;
    #pragma unroll
    for (int k = 0; k < 4; k++){
        int c = c0 + k;
        float mean = sums[c] * invN;
        float var  = sums[64 + c] * invN - mean*mean;
        float rstd = rsqrtf(var + 1e-5f);
        res[k] = g[c]*(hp[k] - mean)*rstd + b[c] + rp[k];
    }
    ((float4*)out)[i] = make_float4(res[0], res[1], res[2], res[3]);
}

// ---------------- link-prediction scores ----------------
__global__ __launch_bounds__(256) void k_score(const float* __restrict__ z, const int* __restrict__ eli,
                                               float* __restrict__ out){
    int t = blockIdx.x*256 + threadIdx.x;
    int i = t >> 4; int j = t & 15;
    if (i >= ELI_N) return;
    int a = eli[i], b = eli[ELI_N + i];
    float4 va = ((const float4*)(z + (size_t)a*64))[j];
    float4 vb = ((const float4*)(z + (size_t)b*64))[j];
    float s = va.x*vb.x + va.y*vb.y + va.z*vb.z + va.w*vb.w;
    #pragma unroll
    for (int off = 8; off > 0; off >>= 1) s += __shfl_xor(s, off, 64);
    if (j == 0) out[i] = 1.f / (1.f + __expf(-s));
}

extern "C" void kernel_launch(void* const* d_in, const int* in_sizes, int n_in,
                              void* d_out, int out_size, void* d_ws, size_t ws_size,
                              hipStream_t stream) {
    const float* x    = (const float*)d_in[0];
    const int*   ei   = (const int*)  d_in[1];
    const int*   eli  = (const int*)  d_in[2];
    const float* Wl1  = (const float*)d_in[3];
    const float* bl1  = (const float*)d_in[4];
    const float* Wr1  = (const float*)d_in[5];
    const float* br1  = (const float*)d_in[6];
    const float* att1 = (const float*)d_in[7];
    const float* bias1= (const float*)d_in[8];
    const float* g1   = (const float*)d_in[9];
    const float* b1   = (const float*)d_in[10];
    const float* Wres = (const float*)d_in[11];
    const float* bres = (const float*)d_in[12];
    const float* Wl2  = (const float*)d_in[13];
    const float* bl2  = (const float*)d_in[14];
    const float* Wr2  = (const float*)d_in[15];
    const float* br2  = (const float*)d_in[16];
    const float* att2 = (const float*)d_in[17];
    const float* bias2= (const float*)d_in[18];
    const float* g2   = (const float*)d_in[19];
    const float* b2   = (const float*)d_in[20];
    float* out = (float*)d_out;

    char* w = (char*)d_ws;
    size_t o = 0;
    auto take = [&](size_t bytes)->char*{ char* p = w + o; o += (bytes + 255) & ~(size_t)255; return p; };
    float* xl   = (float*)take((size_t)NN*HC*4);
    float* xr   = (float*)take((size_t)NN*HC*4);
    float* xres = (float*)take((size_t)NN*CC*4);   // later reused as z
    float* hraw = (float*)take((size_t)NN*CC*4);
    float* hbuf = (float*)take((size_t)NN*CC*4);
    u16* whl1 = (u16*)take(256*128*2);  u16* wll1 = (u16*)take(256*128*2);
    u16* whr1 = (u16*)take(256*128*2);  u16* wlr1 = (u16*)take(256*128*2);
    u16* whres= (u16*)take(64*128*2);   u16* wlres= (u16*)take(64*128*2);
    u16* whl2 = (u16*)take(256*64*2);   u16* wll2 = (u16*)take(256*64*2);
    u16* whr2 = (u16*)take(256*64*2);   u16* wlr2 = (u16*)take(256*64*2);
    // stats (256 floats) + deg (NN ints), contiguous for a single memset
    char* zreg  = take(256*4 + (size_t)NN*4);
    float* stats= (float*)zreg;
    int* deg    = (int*)(zreg + 256*4);
    int* rowptr = (int*)take((size_t)(NN+1)*4);
    int* iscan  = (int*)take((size_t)NN*4);
    int* cursor = (int*)take((size_t)NN*4);
    int* csr_src= (int*)take((size_t)ETOT*4);
    int* part   = (int*)take(64*4);

    hipMemsetAsync(zreg, 0, 256*4 + (size_t)NN*4, stream);

    // CSR build
    k_count<<<(EE+255)/256, 256, 0, stream>>>(ei, deg);
    k_scanA<<<49, 256, 0, stream>>>(deg, iscan, part);
    k_scanC<<<196, 256, 0, stream>>>(iscan, part, deg, rowptr, cursor);
    k_fill<<<(ETOT+255)/256, 256, 0, stream>>>(ei, cursor, csr_src);

    // weights
    k_convW<<<(106496+255)/256, 256, 0, stream>>>(Wl1, Wr1, Wres, Wl2, Wr2,
                                                  whl1, wll1, whr1, wlr1, whres, wlres,
                                                  whl2, wll2, whr2, wlr2);

    // layer 1
    dim3 g1grid(196, 9);
    k_gemm1<<<g1grid, 256, 0, stream>>>(x, whl1, wll1, whr1, wlr1, whres, wlres,
                                        bl1, br1, bres, xl, xr, xres);
    k_gat<<<(NN+3)/4, 256, 0, stream>>>(xl, xr, csr_src, rowptr, att1, bias1, hraw);
    k_bnstats<<<256, 256, 0, stream>>>(hraw, stats);
    k_post1<<<(NN*16+255)/256, 256, 0, stream>>>(hraw, xres, stats, g1, b1, hbuf);

    // layer 2
    dim3 g2grid(196, 8);
    k_gemm2<<<g2grid, 256, 0, stream>>>(hbuf, whl2, wll2, whr2, wlr2, bl2, br2, xl, xr);
    k_gat<<<(NN+3)/4, 256, 0, stream>>>(xl, xr, csr_src, rowptr, att2, bias2, hraw);
    k_bnstats<<<256, 256, 0, stream>>>(hraw, stats + 128);
    k_post2<<<(NN*16+255)/256, 256, 0, stream>>>(hraw, hbuf, stats + 128, g2, b2, xres);

    // scores
    k_score<<<(ELI_N*16+255)/256, 256, 0, stream>>>(xres, eli, out);
}